// Round 14
// baseline (244.578 us; speedup 1.0000x reference)
//
#include <hip/hip_runtime.h>
#include <math.h>

#define B_   4
#define T_   512
#define TAU_ 512
#define L_   1024
#define DM_  1024
#define H_   16
#define D_   64

typedef short  s16x8 __attribute__((ext_vector_type(8)));   // 8 bf16 MFMA frag
typedef ushort u16x4 __attribute__((ext_vector_type(4)));
typedef float  f32x4 __attribute__((ext_vector_type(4)));

__device__ __forceinline__ ushort f2bf(float x) {   // RNE float->bf16 bits
  uint u = __float_as_uint(x);
  u += 0x7fffu + ((u >> 16) & 1u);
  return (ushort)(u >> 16);
}
__device__ __forceinline__ float bf2f(ushort u) {
  return __uint_as_float(((uint)u) << 16);
}
// XOR-swizzle for bf16 [rows][64] LDS tiles (128B rows): permute 16B slots by row&7
__device__ __forceinline__ int sw64(int row, int col) {
  return row * 64 + (col ^ ((row & 7) << 3));
}

// ---------------------------------------------------------------------------
// Fused preprocessing, launch-overhead-minimized (3328 blocks):
// [0,1024)    LayerNorm: one WAVE per row (4 rows/block, no barriers)
// [1024,2048) phi table: 4 elems/thread
// [2048,3328) weight fp32->bf16 casts: 4 float4/thread
// ---------------------------------------------------------------------------
__global__ __launch_bounds__(256) void prep_kernel(
    const float* __restrict__ inp, const float* __restrict__ mem,
    const float* __restrict__ gamma, const float* __restrict__ beta,
    ushort* __restrict__ xn, ushort* __restrict__ phi,
    const float* __restrict__ wq, ushort* __restrict__ wqb,
    const float* __restrict__ wp, ushort* __restrict__ wpb,
    const float* __restrict__ wo, ushort* __restrict__ wob) {
  int blk = blockIdx.x;
  int t = threadIdx.x;
  if (blk < 1024) {                    // ---- LayerNorm, wave per row ----
    int wid = t >> 6, lane = t & 63;
    int row = blk * 4 + wid;           // b*L + l
    int b = row >> 10, l = row & 1023;
    const float* src = (l < TAU_)
        ? mem + ((size_t)b * TAU_ + l) * DM_
        : inp + ((size_t)b * T_ + (l - TAU_)) * DM_;
    float4 v[4];
    float s1 = 0.f, s2 = 0.f;
#pragma unroll
    for (int c = 0; c < 4; ++c) {
      v[c] = *(const float4*)(src + c * 256 + lane * 4);
      s1 += v[c].x + v[c].y + v[c].z + v[c].w;
      s2 += v[c].x * v[c].x + v[c].y * v[c].y + v[c].z * v[c].z + v[c].w * v[c].w;
    }
#pragma unroll
    for (int off = 32; off > 0; off >>= 1) {
      s1 += __shfl_xor(s1, off);
      s2 += __shfl_xor(s2, off);
    }
    float mu   = s1 * (1.0f / DM_);
    float var  = s2 * (1.0f / DM_) - mu * mu;
    float rstd = 1.0f / sqrtf(var + 1e-5f);
#pragma unroll
    for (int c = 0; c < 4; ++c) {
      float4 g  = *(const float4*)(gamma + c * 256 + lane * 4);
      float4 be = *(const float4*)(beta  + c * 256 + lane * 4);
      u16x4 o;
      o[0] = f2bf((v[c].x - mu) * rstd * g.x + be.x);
      o[1] = f2bf((v[c].y - mu) * rstd * g.y + be.y);
      o[2] = f2bf((v[c].z - mu) * rstd * g.z + be.z);
      o[3] = f2bf((v[c].w - mu) * rstd * g.w + be.w);
      *(u16x4*)(xn + (size_t)row * DM_ + c * 256 + lane * 4) = o;
    }
  } else if (blk < 2048) {             // ---- phi ----
    int base = (blk - 1024) * 1024 + t;
#pragma unroll
    for (int it = 0; it < 4; ++it) {
      int idx = base + it * 256;       // 0 .. 1M-1
      int m = idx >> 10, c = idx & 1023;
      float p = (float)(1023 - m);
      int cc = (c < 512) ? c : c - 512;
      float invf = __expf(-((float)(2 * cc) * (1.0f / 1024.0f)) * 9.210340371976184f);
      float a = p * invf;
      phi[idx] = f2bf((c < 512) ? __sinf(a) : __cosf(a));
    }
  } else {                             // ---- weight casts ----
    int base = (blk - 2048) * 1024 + t;   // float4-group index
#pragma unroll
    for (int it = 0; it < 4; ++it) {
      int i = base + it * 256;            // < 1310720 exactly
      const float* src; ushort* dst; int off;
      if (i < 786432)       { src = wq; dst = wqb; off = i; }
      else if (i < 1048576) { src = wp; dst = wpb; off = i - 786432; }
      else                  { src = wo; dst = wob; off = i - 1048576; }
      float4 v = *(const float4*)(src + (size_t)off * 4);
      u16x4 o = { f2bf(v.x), f2bf(v.y), f2bf(v.z), f2bf(v.w) };
      *(u16x4*)(dst + (size_t)off * 4) = o;
    }
  }
}

// ---------------------------------------------------------------------------
// bf16 MFMA NT GEMM, 128x64 tile, BK=64, 24KB LDS -> 6 blocks/CU.
// Pre-offset bases; wave 2x2 grid, each 64 rows x 32 cols (acc[4][2]).
// ---------------------------------------------------------------------------
template <typename CT>
__device__ __forceinline__ void gemm_nt_body_n64(
    const ushort* __restrict__ Arows, const ushort* __restrict__ Brows,
    CT* __restrict__ Crows, int ldc, int K) {
  __shared__ __attribute__((aligned(16))) ushort As[128 * 64];
  __shared__ __attribute__((aligned(16))) ushort Bs[64 * 64];
  int t = threadIdx.x;
  int w = t >> 6, lane = t & 63, g = lane >> 4, low = lane & 15;
  int wr = w >> 1, wc = w & 1;               // each wave: 64 rows x 32 cols
  f32x4 acc[4][2] = {};

  for (int kt = 0; kt < K; kt += 64) {
    __syncthreads();
#pragma unroll
    for (int q = 0; q < 4; ++q) {            // A: 1024 chunks
      int c = t + q * 256;
      int row = c >> 3;
      int gslot = (c & 7) ^ (row & 7);
      const ushort* ga = Arows + (size_t)row * K + kt + gslot * 8;
      __builtin_amdgcn_global_load_lds(
          (const __attribute__((address_space(1))) void*)ga,
          (__attribute__((address_space(3))) void*)&As[(q * 256 + w * 64) * 8],
          16, 0, 0);
    }
#pragma unroll
    for (int q = 0; q < 2; ++q) {            // B: 512 chunks
      int c = t + q * 256;
      int row = c >> 3;
      int gslot = (c & 7) ^ (row & 7);
      const ushort* gb = Brows + (size_t)row * K + kt + gslot * 8;
      __builtin_amdgcn_global_load_lds(
          (const __attribute__((address_space(1))) void*)gb,
          (__attribute__((address_space(3))) void*)&Bs[(q * 256 + w * 64) * 8],
          16, 0, 0);
    }
    __syncthreads();

#pragma unroll
    for (int kc = 0; kc < 2; ++kc) {
      s16x8 af[4], bfr[2];
#pragma unroll
      for (int mi = 0; mi < 4; ++mi) {
        int row = wr * 64 + mi * 16 + low;
        af[mi] = *(const s16x8*)&As[row * 64 + (((4 * kc + g) ^ (row & 7)) * 8)];
      }
#pragma unroll
      for (int ni = 0; ni < 2; ++ni) {
        int col = wc * 32 + ni * 16 + low;
        bfr[ni] = *(const s16x8*)&Bs[col * 64 + (((4 * kc + g) ^ (col & 7)) * 8)];
      }
#pragma unroll
      for (int mi = 0; mi < 4; ++mi)
#pragma unroll
        for (int ni = 0; ni < 2; ++ni)
          acc[mi][ni] = __builtin_amdgcn_mfma_f32_16x16x32_bf16(
              af[mi], bfr[ni], acc[mi][ni], 0, 0, 0);
    }
  }
#pragma unroll
  for (int mi = 0; mi < 4; ++mi)
#pragma unroll
    for (int ni = 0; ni < 2; ++ni)
#pragma unroll
      for (int r = 0; r < 4; ++r) {
        int m = wr * 64 + mi * 16 + 4 * g + r;          // 0..127 tile-local
        int n = wc * 32 + ni * 16 + low;                // 0..63 tile-local
        if constexpr (sizeof(CT) == 2)
          Crows[(size_t)m * ldc + n] = f2bf(acc[mi][ni][r]);
        else
          Crows[(size_t)m * ldc + n] = acc[mi][ni][r];
      }
}

// ---------------------------------------------------------------------------
// Fused projection GEMMs (dead-Q eliminated): KV 1024 + Q 256 + R 128 tiles.
// 1408 blocks = 8 x 176 bijective XCD swizzle.
// ---------------------------------------------------------------------------
__global__ __launch_bounds__(256) void qkv_r_gemm(
    const ushort* __restrict__ xnb, const ushort* __restrict__ wqb,
    ushort* __restrict__ qkvB,
    const ushort* __restrict__ phib, const ushort* __restrict__ wpb,
    ushort* __restrict__ RmB) {
  int orig = blockIdx.x;
  int id = (orig & 7) * 176 + (orig >> 3);
  if (id < 1024) {                     // KV: 32 row-tiles x 32 col-tiles
    int by = id >> 5, bx = id & 31;
    gemm_nt_body_n64<ushort>(
        xnb + (size_t)by * 128 * 1024,
        wqb + (size_t)(1024 + bx * 64) * 1024,
        qkvB + (size_t)by * 128 * 3072 + 1024 + bx * 64, 3072, 1024);
  } else if (id < 1280) {              // Q: 16 row-tiles (2048 rows) x 16 col
    int q = id - 1024;
    int by = q >> 4, bx = q & 15;
    int b = by >> 2;                   // batch; 4 tiles per 512-row span
    size_t arow = (size_t)b * 1024 + 512 + (by & 3) * 128;
    gemm_nt_body_n64<ushort>(
        xnb + arow * 1024,
        wqb + (size_t)bx * 64 * 1024,
        qkvB + arow * 3072 + bx * 64, 3072, 1024);
  } else {                             // R: 8 row-tiles x 16 col-tiles
    int rr = id - 1280;
    int by = rr >> 4, bx = rr & 15;
    gemm_nt_body_n64<ushort>(
        phib + (size_t)by * 128 * 1024,
        wpb + (size_t)bx * 64 * 1024,
        RmB + (size_t)by * 128 * 1024 + bx * 64, 1024, 1024);
  }
}

// out GEMM: 2048x1024, 128x64 tiles -> 256 blocks (8 x 32 XCD swizzle).
__global__ __launch_bounds__(256) void out_gemm(
    const ushort* __restrict__ attnb, const ushort* __restrict__ wob,
    float* __restrict__ out) {
  int orig = blockIdx.x;
  int id = (orig & 7) * 32 + (orig >> 3);
  int by = id >> 4, bx = id & 15;
  gemm_nt_body_n64<float>(
      attnb + (size_t)by * 128 * 1024,
      wob + (size_t)bx * 64 * 1024,
      out + (size_t)by * 128 * 1024 + bx * 64, 1024, 1024);
}

// ---------------------------------------------------------------------------
// MFMA bf16 flash attention, j-SPLIT (round-10 body otherwise):
// 1024 blocks = (b,h,bi) x 2 j-halves. LDS cut 72->40KB (R staging replaced
// by direct L2-hot fragment loads, 5 live at a time) -> 4 blocks/CU for 2x
// latency hiding (grid was the residency limiter at 512 blocks).
// Each half emits unnormalized fp32 partials (O, m, l); attn_merge_kernel
// does the flash merge. XCD swizzle keeps families on one XCD; slot
// interleave balances each co-resident quad to 25 tiles.
// ---------------------------------------------------------------------------
__global__ void attn_mfma_kernel(
    const ushort* __restrict__ qkv, const ushort* __restrict__ Rm,
    const float* __restrict__ uvar, const float* __restrict__ vvar,
    float* __restrict__ Opart, float* __restrict__ Mp, float* __restrict__ Lp) {
  __shared__ __attribute__((aligned(16))) ushort Ks[2][64 * 64];
  __shared__ __attribute__((aligned(16))) ushort Vt[2][64 * 64];
  __shared__ __attribute__((aligned(16))) ushort Pp[4][16 * 64];

  int t   = threadIdx.x;
  int w   = t >> 6;          // wave 0..3
  int lw  = t & 63;
  int g   = lw >> 4;         // k-group 0..3
  int low = lw & 15;

  int orig = blockIdx.x;     // XCD = orig & 7 (round-robin model)
  int lin  = (orig & 7) * 128 + (orig >> 3);  // XCD owns 128 consecutive
  int fam  = lin >> 4;                        // (b,h) family
  int s    = lin & 15;
  int slot = s >> 1;
  int half = s & 1;
  int h    = fam & 15;
  int b    = fam >> 4;
  int bi   = (slot & 1) ? (7 - (slot >> 1)) : (slot >> 1);  // quad-balance
  int i0   = bi * 64;
  int lb_w = 48 - 16 * w;    // wave's P m-window base

  auto stage_k = [&](int buf, int tl) {
    int j0s = tl * 64;
#pragma unroll
    for (int q = 0; q < 2; ++q) {
      int c = t + q * 256;                  // 16B chunk id 0..511
      int row = c >> 3;
      int sl = (c & 7) ^ (row & 7);
      const ushort* srck = qkv + (size_t)(b * L_ + j0s + row) * 3072 +
                           1024 + h * 64 + sl * 8;
      __builtin_amdgcn_global_load_lds(
          (const __attribute__((address_space(1))) void*)srck,
          (__attribute__((address_space(3))) void*)&Ks[buf][(q * 256 + w * 64) * 8],
          16, 0, 0);
    }
  };

  // V staging: reg-load (issue early) ...
  int vj  = t & 63;                         // wave-local j column
  int vd0 = (t >> 6) * 8;                   // wave-uniform d base (0,8,16,24)
  float4 vreg[2];
  auto vload = [&](int tl) {
    const ushort* p = qkv + (size_t)(b * L_ + tl * 64 + vj) * 3072 + 2048 + h * 64;
    vreg[0] = *(const float4*)(p + vd0);
    vreg[1] = *(const float4*)(p + vd0 + 32);
  };
  auto vwrite = [&](int buf) {
#pragma unroll
    for (int it = 0; it < 2; ++it) {
      ushort vals[8];
      *(float4*)vals = vreg[it];
#pragma unroll
      for (int e = 0; e < 8; ++e) {
        int d = it * 32 + vd0 + e;
        Vt[buf][d * 64 + (vj ^ ((d & 7) << 3))] = vals[e];
      }
    }
  };

  // Q fragments (bf16 source + fp32 u/v), loaded once
  int iq = i0 + 16 * w + low;
  s16x8 qu[2], qv[2];
  {
    const ushort* qrow = qkv + (size_t)(b * L_ + TAU_ + iq) * 3072 + h * 64;
    const float* ur = uvar + h * 64;
    const float* vr = vvar + h * 64;
#pragma unroll
    for (int kc = 0; kc < 2; ++kc) {
      int dbase = kc * 32 + 8 * g;
#pragma unroll
      for (int e = 0; e < 8; ++e) {
        float q = bf2f(qrow[dbase + e]);
        qu[kc][e] = (short)f2bf(q + ur[dbase + e]);
        qv[kc][e] = (short)f2bf(q + vr[dbase + e]);
      }
    }
  }

  f32x4 O[4] = {};
  float mreg[4] = {-INFINITY, -INFINITY, -INFINITY, -INFINITY};
  float lreg[4] = {0.f, 0.f, 0.f, 0.f};

  int nt_tot = 9 + bi;
  int nt0    = (nt_tot + 1) >> 1;
  int tstart = half ? nt0 : 0;
  int tend   = half ? nt_tot : nt0;

  stage_k(0, tstart);
  vload(tstart);
  vwrite(0);
  __syncthreads();           // tile tstart ready
  int cur = 0;
  for (int tile = tstart; tile < tend; ++tile) {
    int j0 = tile * 64;
    bool more = (tile + 1 < tend);
    if (more) { stage_k(cur ^ 1, tile + 1); vload(tile + 1); }

    int mb = j0 + 448 - i0;
    // ---- R fragments kc=0, direct from global (L2-hot; overlap QK^T) ----
    s16x8 rb[5];
#pragma unroll
    for (int mt = 0; mt < 5; ++mt) {
      int m = mb + lb_w + mt * 16 + low;
      m = (m > 1023) ? 1023 : m;
      rb[mt] = *(const s16x8*)(Rm + (size_t)m * 1024 + h * 64 + 8 * g);
    }
    // ---- QK^T ----
    f32x4 s4[4] = {};
#pragma unroll
    for (int jt = 0; jt < 4; ++jt) {
#pragma unroll
      for (int kc = 0; kc < 2; ++kc) {
        s16x8 kb = *(const s16x8*)&Ks[cur][sw64(jt * 16 + low, kc * 32 + 8 * g)];
        s4[jt] = __builtin_amdgcn_mfma_f32_16x16x32_bf16(qu[kc], kb, s4[jt], 0, 0, 0);
      }
    }
    // ---- P kc=0 ----
    f32x4 p[5] = {};
#pragma unroll
    for (int mt = 0; mt < 5; ++mt)
      p[mt] = __builtin_amdgcn_mfma_f32_16x16x32_bf16(qv[0], rb[mt], p[mt], 0, 0, 0);
    // ---- R fragments kc=1 + P kc=1 ----
#pragma unroll
    for (int mt = 0; mt < 5; ++mt) {
      int m = mb + lb_w + mt * 16 + low;
      m = (m > 1023) ? 1023 : m;
      rb[mt] = *(const s16x8*)(Rm + (size_t)m * 1024 + h * 64 + 32 + 8 * g);
    }
#pragma unroll
    for (int mt = 0; mt < 5; ++mt)
      p[mt] = __builtin_amdgcn_mfma_f32_16x16x32_bf16(qv[1], rb[mt], p[mt], 0, 0, 0);

    // ---- rel-shift via shfl + mask ----
#pragma unroll
    for (int r = 0; r < 4; ++r) {
      int iL = 4 * g + r;
      int src = g * 16 + ((low + 15 - iL) & 15);   // D-layout: col=lane&15
      float sh0 = __shfl(p[0][r], src);
      float sh1 = __shfl(p[1][r], src);
      float sh2 = __shfl(p[2][r], src);
      float sh3 = __shfl(p[3][r], src);
      float sh4 = __shfl(p[4][r], src);
      bool lo = (low <= iL);
      float po0 = lo ? sh0 : sh1;
      float po1 = lo ? sh1 : sh2;
      float po2 = lo ? sh2 : sh3;
      float po3 = lo ? sh3 : sh4;
      int lim = TAU_ + i0 + 16 * w + iL;
      s4[0][r] = (j0 +  0 + low <= lim) ? (s4[0][r] + po0) * 0.125f : -1e30f;
      s4[1][r] = (j0 + 16 + low <= lim) ? (s4[1][r] + po1) * 0.125f : -1e30f;
      s4[2][r] = (j0 + 32 + low <= lim) ? (s4[2][r] + po2) * 0.125f : -1e30f;
      s4[3][r] = (j0 + 48 + low <= lim) ? (s4[3][r] + po3) * 0.125f : -1e30f;
    }
    // ---- online softmax ----
#pragma unroll
    for (int r = 0; r < 4; ++r) {
      float mx = fmaxf(fmaxf(s4[0][r], s4[1][r]), fmaxf(s4[2][r], s4[3][r]));
      mx = fmaxf(mx, __shfl_xor(mx, 1));
      mx = fmaxf(mx, __shfl_xor(mx, 2));
      mx = fmaxf(mx, __shfl_xor(mx, 4));
      mx = fmaxf(mx, __shfl_xor(mx, 8));
      float mn = fmaxf(mreg[r], mx);
      float alpha = __expf(mreg[r] - mn);
      mreg[r] = mn;
      float sum = 0.f;
#pragma unroll
      for (int jt = 0; jt < 4; ++jt) {
        float pe = __expf(s4[jt][r] - mn);
        s4[jt][r] = pe;
        sum += pe;
      }
      sum += __shfl_xor(sum, 1);
      sum += __shfl_xor(sum, 2);
      sum += __shfl_xor(sum, 4);
      sum += __shfl_xor(sum, 8);
      lreg[r] = lreg[r] * alpha + sum;
      O[0][r] *= alpha; O[1][r] *= alpha; O[2][r] *= alpha; O[3][r] *= alpha;
    }
    // ---- P -> bf16 LDS (C-layout -> A-layout transpose) ----
#pragma unroll
    for (int jt = 0; jt < 4; ++jt)
#pragma unroll
      for (int r = 0; r < 4; ++r)
        Pp[w][sw64(4 * g + r, jt * 16 + low)] = f2bf(s4[jt][r]);
    asm volatile("s_waitcnt lgkmcnt(0)" ::: "memory");
    s16x8 pa0 = *(const s16x8*)&Pp[w][sw64(low, 8 * g)];
    s16x8 pa1 = *(const s16x8*)&Pp[w][sw64(low, 32 + 8 * g)];
    // ---- PV ----
#pragma unroll
    for (int dt = 0; dt < 4; ++dt) {
      s16x8 v0 = *(const s16x8*)&Vt[cur][sw64(dt * 16 + low, 8 * g)];
      s16x8 v1 = *(const s16x8*)&Vt[cur][sw64(dt * 16 + low, 32 + 8 * g)];
      O[dt] = __builtin_amdgcn_mfma_f32_16x16x32_bf16(pa0, v0, O[dt], 0, 0, 0);
      O[dt] = __builtin_amdgcn_mfma_f32_16x16x32_bf16(pa1, v1, O[dt], 0, 0, 0);
    }
    if (more) vwrite(cur ^ 1);   // V transpose-write for next tile (late)
    __syncthreads();             // LDS reads done + DMA landed + V writes vis
    cur ^= 1;
  }
  // epilogue: write UNNORMALIZED fp32 partial + per-row m,l (part index = lin)
  size_t pbase = (size_t)lin * 4096;
#pragma unroll
  for (int dt = 0; dt < 4; ++dt)
#pragma unroll
    for (int r = 0; r < 4; ++r)
      Opart[pbase + (size_t)(16 * w + 4 * g + r) * 64 + dt * 16 + low] = O[dt][r];
  if (low == 0) {
#pragma unroll
    for (int r = 0; r < 4; ++r) {
      Mp[lin * 64 + 16 * w + 4 * g + r] = mreg[r];
      Lp[lin * 64 + 16 * w + 4 * g + r] = lreg[r];
    }
  }
}

// ---------------------------------------------------------------------------
// Flash merge of the two j-halves: O = (O0*e^{m0-m} + O1*e^{m1-m}) / l.
// 512 blocks x 256 thr; thread handles one row-quarter (16 cols).
// ---------------------------------------------------------------------------
__global__ __launch_bounds__(256) void attn_merge_kernel(
    const float* __restrict__ Opart, const float* __restrict__ Mp,
    const float* __restrict__ Lp, ushort* __restrict__ attn) {
  int id = blockIdx.x;               // fam*8 + slot
  int fam = id >> 3, slot = id & 7;
  int bi = (slot & 1) ? (7 - (slot >> 1)) : (slot >> 1);
  int b = fam >> 4, h = fam & 15;
  int i0 = bi * 64;
  int t = threadIdx.x;
  int row = t >> 2;                  // 0..63
  int c0  = (t & 3) * 16;
  int p0i = id * 2, p1i = id * 2 + 1;
  float m0 = Mp[p0i * 64 + row], m1 = Mp[p1i * 64 + row];
  float l0 = Lp[p0i * 64 + row], l1 = Lp[p1i * 64 + row];
  float m  = fmaxf(m0, m1);
  float a0 = __expf(m0 - m), a1 = __expf(m1 - m);
  float inv = 1.0f / (l0 * a0 + l1 * a1);
  const float4* O0 = (const float4*)(Opart + (size_t)p0i * 4096 + row * 64 + c0);
  const float4* O1 = (const float4*)(Opart + (size_t)p1i * 4096 + row * 64 + c0);
  ushort* dst = attn + ((size_t)(b * T_ + i0 + row)) * 1024 + h * 64 + c0;
#pragma unroll
  for (int q = 0; q < 4; ++q) {
    float4 x0 = O0[q], x1 = O1[q];
    u16x4 o;
    o[0] = f2bf((x0.x * a0 + x1.x * a1) * inv);
    o[1] = f2bf((x0.y * a0 + x1.y * a1) * inv);
    o[2] = f2bf((x0.z * a0 + x1.z * a1) * inv);
    o[3] = f2bf((x0.w * a0 + x1.w * a1) * inv);
    *(u16x4*)(dst + q * 4) = o;
  }
}

// ---------------------------------------------------------------------------
extern "C" void kernel_launch(void* const* d_in, const int* in_sizes, int n_in,
                              void* d_out, int out_size, void* d_ws, size_t ws_size,
                              hipStream_t stream) {
  const float* inputs = (const float*)d_in[0];
  const float* memory = (const float*)d_in[1];
  const float* w_qkv  = (const float*)d_in[2];
  const float* w_pos  = (const float*)d_in[3];
  const float* w_out  = (const float*)d_in[4];
  const float* uvar   = (const float*)d_in[5];
  const float* vvar   = (const float*)d_in[6];
  const float* gamma  = (const float*)d_in[7];
  const float* beta   = (const float*)d_in[8];
  float* out = (float*)d_out;

  // workspace layout: 48.2 MB bf16 + 17.3 MB fp32 partials = 65.5 MB
  ushort* qkvB = (ushort*)d_ws;                       // 4096*3072
  ushort* xnb  = qkvB + (size_t)4096 * 3072;          // 4096*1024
  ushort* phib = xnb  + (size_t)4096 * 1024;          // 1024*1024
  ushort* RmB  = phib + (size_t)1024 * 1024;          // 1024*1024
  ushort* wqb  = RmB  + (size_t)1024 * 1024;          // 3072*1024
  ushort* wpb  = wqb  + (size_t)3072 * 1024;          // 1024*1024
  ushort* wob  = wpb  + (size_t)1024 * 1024;          // 1024*1024
  float*  Opart = (float*)(wob + (size_t)1024 * 1024);// 1024*4096 f32
  float*  Mp    = Opart + (size_t)1024 * 4096;        // 1024*64
  float*  Lp    = Mp + 1024 * 64;                     // 1024*64
  ushort* attnb = xnb;                                // reuse after QKV GEMM

  prep_kernel<<<3328, 256, 0, stream>>>(inputs, memory, gamma, beta, xnb,
                                        phib, w_qkv, wqb, w_pos, wpb, w_out, wob);
  qkv_r_gemm<<<1408, 256, 0, stream>>>(xnb, wqb, qkvB, phib, wpb, RmB);
  attn_mfma_kernel<<<1024, 256, 0, stream>>>(qkvB, RmB, uvar, vvar, Opart, Mp, Lp);
  attn_merge_kernel<<<512, 256, 0, stream>>>(Opart, Mp, Lp, attnb);
  out_gemm<<<256, 256, 0, stream>>>(attnb, wob, out);
}